// Round 6
// baseline (139.000 us; speedup 1.0000x reference)
//
#include <hip/hip_runtime.h>
#include <hip/hip_bf16.h>

// DWT 2D low-pass = separable 4-tap stride-2 stencil:
//   out[p,q] = sum_{i,j} f[i]*f[j] * x[2p-1+i, 2q-1+j], OOB -> 0
// f[j] = matrix_h[1][1+j] (db2 reconstruction low-pass taps).
//
// One wave spans the full 512-col input row: lane l loads cols 8l..8l+7 via
// two aligned nontemporal float4 loads (input is never reused -> bypass L2),
// produces output cols 4l..4l+3 (one float4 NT store). Horizontal halo =
// 1 shfl_up + 1 shfl_down per input row; wave edge == image edge.
// Vertical edges: clamped row addresses + multiplicative masks (no
// conditional loads). Each wave owns a 16-row output strip; unroll 8 +
// launch_bounds(256,4) (<=128 VGPR) gives a deep in-flight load window.

#define DWT_H 512
#define DWT_W 512
#define DWT_PH 256
#define DWT_PW 256
#define WAVE_S 16   // output rows per wave

typedef float f32x4 __attribute__((ext_vector_type(4)));  // NT-legal vec

__device__ __forceinline__ float4 colf(const float* __restrict__ p, int lane,
                                       float f0, float f1, float f2, float f3)
{
    const f32x4 av = __builtin_nontemporal_load(reinterpret_cast<const f32x4*>(p));
    const f32x4 bv = __builtin_nontemporal_load(reinterpret_cast<const f32x4*>(p + 4));
    float left  = __shfl_up(bv.w, 1, 64);          // x[8l-1]
    float right = __shfl_down(av.x, 1, 64);        // x[8l+8]
    if (lane == 0)  left  = 0.f;                   // image left edge
    if (lane == 63) right = 0.f;                   // image right edge
    float4 r;
    r.x = f0 * left + f1 * av.x + f2 * av.y + f3 * av.z;
    r.y = f0 * av.y + f1 * av.z + f2 * av.w + f3 * bv.x;
    r.z = f0 * av.w + f1 * bv.x + f2 * bv.y + f3 * bv.z;
    r.w = f0 * bv.y + f1 * bv.z + f2 * bv.w + f3 * right;
    return r;
}

__global__ __launch_bounds__(256, 4)
void dwt2d_low_kernel(const float* __restrict__ x,
                      const float* __restrict__ mh,
                      float* __restrict__ out)
{
    const int lane = threadIdx.x & 63;
    const int wv   = threadIdx.x >> 6;                     // 0..3
    const int bc   = blockIdx.y;
    const int p0   = blockIdx.x * (4 * WAVE_S) + wv * WAVE_S;

    // filter taps: matrix_h[1][1..4] == band_low[0..3] (uniform -> SGPR)
    const float f0 = mh[DWT_W + 1];
    const float f1 = mh[DWT_W + 2];
    const float f2 = mh[DWT_W + 3];
    const float f3 = mh[DWT_W + 4];

    const float* xi = x + (size_t)bc * DWT_H * DWT_W + 8 * lane;
    float* yo = out + (size_t)bc * DWT_PH * DWT_PW
                    + (size_t)p0 * DWT_PW + 4 * lane;

    // prologue rows 2p0-1 (clamped+masked) and 2p0 (always valid)
    const int   gr0  = 2 * p0 - 1;
    const float mtop = (gr0 >= 0) ? 1.f : 0.f;
    float4 rv0 = colf(xi + (ptrdiff_t)max(gr0, 0) * DWT_W, lane, f0, f1, f2, f3);
    rv0.x *= mtop; rv0.y *= mtop; rv0.z *= mtop; rv0.w *= mtop;
    float4 rv1 = colf(xi + (ptrdiff_t)(2 * p0) * DWT_W, lane, f0, f1, f2, f3);

    #pragma unroll 8
    for (int i = 0; i < WAVE_S; ++i) {
        const int p  = p0 + i;
        const int g2 = 2 * p + 2;                          // ==512 only at p==255
        const float mb = (g2 < DWT_H) ? 1.f : 0.f;
        float4 rv2 = colf(xi + (ptrdiff_t)(2 * p + 1) * DWT_W, lane, f0, f1, f2, f3);
        float4 rv3 = colf(xi + (ptrdiff_t)min(g2, DWT_H - 1) * DWT_W, lane, f0, f1, f2, f3);
        rv3.x *= mb; rv3.y *= mb; rv3.z *= mb; rv3.w *= mb;
        f32x4 o;
        o.x = f0 * rv0.x + f1 * rv1.x + f2 * rv2.x + f3 * rv3.x;
        o.y = f0 * rv0.y + f1 * rv1.y + f2 * rv2.y + f3 * rv3.y;
        o.z = f0 * rv0.z + f1 * rv1.z + f2 * rv2.z + f3 * rv3.z;
        o.w = f0 * rv0.w + f1 * rv1.w + f2 * rv2.w + f3 * rv3.w;
        __builtin_nontemporal_store(o, reinterpret_cast<f32x4*>(yo + (size_t)i * DWT_PW));
        rv0 = rv2;
        rv1 = rv3;
    }
}

extern "C" void kernel_launch(void* const* d_in, const int* in_sizes, int n_in,
                              void* d_out, int out_size, void* d_ws, size_t ws_size,
                              hipStream_t stream)
{
    const float* x  = (const float*)d_in[0];   // (B,C,512,512) fp32
    const float* mh = (const float*)d_in[1];   // (256,512) fp32
    float* out      = (float*)d_out;           // (B,C,256,256) fp32

    const int bc = in_sizes[0] / (DWT_H * DWT_W);   // B*C = 512

    dim3 grid(DWT_PH / (4 * WAVE_S), bc);           // 4 x 512 = 2048 blocks
    dim3 block(256);
    dwt2d_low_kernel<<<grid, block, 0, stream>>>(x, mh, out);
}